// Round 4
// baseline (1253.872 us; speedup 1.0000x reference)
//
#include <hip/hip_runtime.h>
#include <hip/hip_bf16.h>
#include <math.h>

// SSMBlock: B=8, T=2048, C=1024, NF=64. R = 16384 rows.
// Round 8: PERSISTENT scan. One dispatch runs all 11 steps with a manual
// device-scope grid barrier between steps (sense-reversing, self-restoring,
// bounded spin). Kernel body (P0 sincos / P1 z2^T MFMA / P2 mmnorm / G')
// identical to round 7. Co-residency: 128KB LDS -> 1 block/CU, grid 256 = CUs.
// ws: Xb 32M | Qb 32M | Vb 32M | aWt 4M | pWt 2M | w2t/.w1f 512K | Ga/Gb 16M |
//     fid 256B | bar 8B

#define R_ROWS 16384
#define T_DIM  2048
#define C_DIM  1024

typedef unsigned short u16;
typedef __attribute__((ext_vector_type(8))) short short8;
typedef __attribute__((ext_vector_type(4))) float f32x4;

__device__ __forceinline__ u16 f2bf(float f) {
  union { float f; unsigned u; } v; v.f = f;
  unsigned r = v.u + 0x7fffu + ((v.u >> 16) & 1u);
  return (u16)(r >> 16);
}
__device__ __forceinline__ float bf2f(u16 h) {
  union { unsigned u; float f; } v; v.u = ((unsigned)h) << 16;
  return v.f;
}
__device__ __forceinline__ void gld16(const void* g, void* l) {
  __builtin_amdgcn_global_load_lds(
      (const __attribute__((address_space(1))) void*)g,
      (__attribute__((address_space(3))) void*)l, 16, 0, 0);
}

// Sense-reversing grid barrier for exactly 256 co-resident blocks.
// bar[0]=count, bar[1]=generation. Self-restoring (cnt ends at 0).
__device__ __forceinline__ void grid_barrier(unsigned* bar) {
  __syncthreads();
  if (threadIdx.x == 0) {
    __threadfence();  // flush this block's stores (L2 writeback, device scope)
    const unsigned g =
        __hip_atomic_load(&bar[1], __ATOMIC_RELAXED, __HIP_MEMORY_SCOPE_AGENT);
    const unsigned a =
        __hip_atomic_fetch_add(&bar[0], 1u, __ATOMIC_ACQ_REL, __HIP_MEMORY_SCOPE_AGENT);
    if (a == 255u) {
      __hip_atomic_store(&bar[0], 0u, __ATOMIC_RELAXED, __HIP_MEMORY_SCOPE_AGENT);
      __hip_atomic_fetch_add(&bar[1], 1u, __ATOMIC_RELEASE, __HIP_MEMORY_SCOPE_AGENT);
    } else {
      int spins = 0;
      while (__hip_atomic_load(&bar[1], __ATOMIC_ACQUIRE,
                               __HIP_MEMORY_SCOPE_AGENT) == g) {
        __builtin_amdgcn_s_sleep(2);
        if (++spins > (1 << 22)) break;  // safety: never hang forever
      }
    }
    __threadfence();  // invalidate stale L1/L2 lines before readers proceed
  }
  __syncthreads();
}

// ---------------- elementwise ----------------------------------------------
__global__ __launch_bounds__(256) void cvt_bf16(const float* __restrict__ in,
                                                u16* __restrict__ out, int n8) {
  const int i = blockIdx.x * 256 + threadIdx.x;
  if (i >= n8) return;
  const float4 a = ((const float4*)in)[2 * i];
  const float4 b = ((const float4*)in)[2 * i + 1];
  alignas(16) u16 t[8] = {f2bf(a.x), f2bf(a.y), f2bf(a.z), f2bf(a.w),
                          f2bf(b.x), f2bf(b.y), f2bf(b.z), f2bf(b.w)};
  ((uint4*)out)[i] = *(const uint4*)t;
}

__global__ __launch_bounds__(256) void prod_bf16(const u16* __restrict__ a,
                                                 const u16* __restrict__ b,
                                                 u16* __restrict__ o, int n8) {
  const int i = blockIdx.x * 256 + threadIdx.x;
  if (i >= n8) return;
  uint4 ua = ((const uint4*)a)[i], ub = ((const uint4*)b)[i];
  const u16* pa = (const u16*)&ua;
  const u16* pb = (const u16*)&ub;
  alignas(16) u16 t[8];
#pragma unroll
  for (int c = 0; c < 8; c++) t[c] = f2bf(bf2f(pa[c]) * bf2f(pb[c]));
  ((uint4*)o)[i] = *(const uint4*)t;
}

// ---------------- weight prep ----------------------------------------------
__global__ __launch_bounds__(256) void cvt_T(const float* __restrict__ W,
                                             u16* __restrict__ Wt, int K, int N) {
  __shared__ float t[32][33];
  const int k0 = blockIdx.x * 32, n0 = blockIdx.y * 32;
  const int tx = threadIdx.x & 31, ty = threadIdx.x >> 5;
#pragma unroll
  for (int i = 0; i < 32; i += 8)
    t[ty + i][tx] = W[(size_t)(k0 + ty + i) * N + n0 + tx];
  __syncthreads();
#pragma unroll
  for (int i = 0; i < 32; i += 8)
    Wt[(size_t)(n0 + ty + i) * K + k0 + tx] = f2bf(t[tx][ty + i]);
}

// freq_W [2048][64] -> W1f [128][1024]: rows 0..63 = top (k<1024), 64..127 = bot
__global__ __launch_bounds__(256) void cvt_w1f(const float* __restrict__ W,
                                               u16* __restrict__ W1f) {
  __shared__ float t[32][33];
  const int k0 = blockIdx.x * 32, n0 = blockIdx.y * 32;
  const int tx = threadIdx.x & 31, ty = threadIdx.x >> 5;
#pragma unroll
  for (int i = 0; i < 32; i += 8)
    t[ty + i][tx] = W[(size_t)(k0 + ty + i) * 64 + n0 + tx];
  __syncthreads();
#pragma unroll
  for (int i = 0; i < 32; i += 8) {
    const int k = k0 + tx;
    const int row = (n0 + ty + i) + ((k >= 1024) ? 64 : 0);
    W1f[(size_t)row * 1024 + (k & 1023)] = f2bf(t[tx][ty + i]);
  }
}

// fid[j] = sum_{k<1024} identity[k] * freq_W[k][j]
__global__ __launch_bounds__(256) void fid_kernel(const float* __restrict__ ident,
                                                  const float* __restrict__ W,
                                                  float* __restrict__ fid) {
  __shared__ float red[256];
  const int tid = threadIdx.x;
  const int j = tid >> 2, part = tid & 3;
  float s = 0.f;
  for (int k = part * 256; k < part * 256 + 256; k++)
    s += ident[k] * W[(size_t)k * 64 + j];
  red[tid] = s;
  __syncthreads();
  if (part == 0) fid[j] = red[tid] + red[tid + 1] + red[tid + 2] + red[tid + 3];
}

// ---------------- big GEMMs (m97-style + XCD swizzle) -----------------------
#define GEMM_KLOOP(Aptr, Bptr)                                                 \
  const int tid = threadIdx.x, lane = tid & 63, w = tid >> 6;                  \
  const int ln = lane & 15, qd = lane >> 4;                                    \
  const int wm = w & 1, wn = w >> 1;                                           \
  const int nbx = gridDim.x;                                                   \
  const int bid0 = blockIdx.y * nbx + blockIdx.x;                              \
  const int nwg = nbx * gridDim.y;                                             \
  const int bid = (bid0 & 7) * (nwg >> 3) + (bid0 >> 3);                       \
  const int n0 = (bid % nbx) * 128, m0 = (bid / nbx) * 128;                    \
  const int srow = w * 32 + (lane >> 3);                                       \
  const int sl = (lane & 7) ^ ((lane >> 3) & 7);                               \
  const int scol = sl * 8;                                                     \
  f32x4 acc[4][4] = {};                                                        \
  for (int kt = 0; kt < 1024; kt += 64) {                                      \
    __syncthreads();                                                           \
    _Pragma("unroll") for (int j = 0; j < 4; j++) {                            \
      gld16(&Aptr[(size_t)(m0 + srow + j * 8) * 1024 + kt + scol],             \
            &As[(w * 32 + j * 8) * 64]);                                       \
      gld16(&Bptr[(size_t)(n0 + srow + j * 8) * 1024 + kt + scol],             \
            &Bs[(w * 32 + j * 8) * 64]);                                       \
    }                                                                          \
    __syncthreads();                                                           \
    _Pragma("unroll") for (int ks = 0; ks < 2; ks++) {                         \
      short8 af[4], bf_[4];                                                    \
      _Pragma("unroll") for (int i = 0; i < 4; i++) {                          \
        const int ar = wm * 64 + i * 16 + ln;                                  \
        af[i] = *(const short8*)&As[ar * 64 + ((ks * 4 + qd) ^ (ar & 7)) * 8]; \
      }                                                                        \
      _Pragma("unroll") for (int j = 0; j < 4; j++) {                          \
        const int br = wn * 64 + j * 16 + ln;                                  \
        bf_[j] = *(const short8*)&Bs[br * 64 + ((ks * 4 + qd) ^ (br & 7)) * 8];\
      }                                                                        \
      _Pragma("unroll") for (int i = 0; i < 4; i++)                            \
      _Pragma("unroll") for (int j = 0; j < 4; j++)                            \
        acc[i][j] = __builtin_amdgcn_mfma_f32_16x16x32_bf16(af[i], bf_[j],     \
                                                            acc[i][j], 0, 0, 0);\
    }                                                                          \
  }                                                                            \
  __syncthreads();

__global__ __launch_bounds__(256) void gemm_qv_mfma(
    const u16* __restrict__ A, const u16* __restrict__ Bt,
    const float* __restrict__ bias, u16* __restrict__ Qb, u16* __restrict__ Vb) {
  __shared__ u16 S[16384];
  u16* As = S;
  u16* Bs = S + 8192;
  GEMM_KLOOP(A, Bt)
#pragma unroll
  for (int j = 0; j < 4; j++) {
    const int col = wn * 64 + j * 16 + ln;
    const float bv = bias[n0 + col];
#pragma unroll
    for (int i = 0; i < 4; i++)
#pragma unroll
      for (int r = 0; r < 4; r++)
        S[(wm * 64 + i * 16 + qd * 4 + r) * 128 + col] = f2bf(acc[i][j][r] + bv);
  }
  __syncthreads();
  const bool isQ = (n0 < 1024);
  u16* dst = isQ ? Qb : Vb;
  const int nb = isQ ? n0 : n0 - 1024;
#pragma unroll
  for (int it = 0; it < 8; it++) {
    const int idx = it * 256 + tid;
    const int row = idx >> 4, seg = idx & 15;
    *(uint4*)&dst[(size_t)(m0 + row) * 1024 + nb + seg * 8] = ((const uint4*)S)[idx];
  }
}

__global__ __launch_bounds__(256) void gemm_proj_mfma(
    const u16* __restrict__ A, const u16* __restrict__ Bt,
    const float* __restrict__ bias, float* __restrict__ OUT) {
  __shared__ u16 S[16384];
  u16* As = S;
  u16* Bs = S + 8192;
  GEMM_KLOOP(A, Bt)
  float* Csf = (float*)S;
#pragma unroll
  for (int p = 0; p < 2; p++) {
    if (wm == p) {
#pragma unroll
      for (int j = 0; j < 4; j++) {
        const int col = wn * 64 + j * 16 + ln;
        const float bv = bias[n0 + col];
#pragma unroll
        for (int i = 0; i < 4; i++)
#pragma unroll
          for (int r = 0; r < 4; r++)
            Csf[(i * 16 + qd * 4 + r) * 128 + col] = acc[i][j][r] + bv;
      }
    }
    __syncthreads();
#pragma unroll
    for (int it = 0; it < 8; it++) {
      const int idx = it * 256 + tid;
      const int row = idx >> 5, seg = idx & 31;
      *(uint4*)&OUT[(size_t)(m0 + p * 64 + row) * 1024 + n0 + seg * 4] =
          ((const uint4*)Csf)[idx];
    }
    __syncthreads();
  }
}

// ---------------- G0 = q @ W1full : M=16384 N=128 K=1024 --------------------
__global__ __launch_bounds__(256) void g0_kernel(const u16* __restrict__ Qb,
                                                 const u16* __restrict__ W1f,
                                                 float* __restrict__ G) {
  __shared__ u16 As[64 * 64];  // 8KB
  const int tid = threadIdx.x, lane = tid & 63, wv = tid >> 6;
  const int ln = lane & 15, qd = lane >> 4;
  const int wm = wv >> 1, wn = wv & 1;
  const int m0 = blockIdx.x * 64;
  const int srow = wv * 16 + (lane >> 3);
  const int scol = ((lane & 7) ^ ((lane >> 3) & 7)) * 8;
  f32x4 acc[2][4] = {};
  for (int kt = 0; kt < 1024; kt += 64) {
    __syncthreads();
#pragma unroll
    for (int j = 0; j < 2; j++)
      gld16(&Qb[(size_t)(m0 + srow + j * 8) * 1024 + kt + scol],
            &As[(wv * 16 + j * 8) * 64]);
    __syncthreads();
#pragma unroll
    for (int ks = 0; ks < 2; ks++) {
      short8 a[2];
#pragma unroll
      for (int i = 0; i < 2; i++) {
        const int ar = wm * 32 + i * 16 + ln;
        a[i] = *(const short8*)&As[ar * 64 + ((ks * 4 + qd) ^ (ar & 7)) * 8];
      }
#pragma unroll
      for (int nt = 0; nt < 4; nt++) {
        const short8 b = *(const short8*)&W1f[(size_t)(wn * 64 + nt * 16 + ln) * 1024 +
                                              kt + ks * 32 + qd * 8];
#pragma unroll
        for (int i = 0; i < 2; i++)
          acc[i][nt] = __builtin_amdgcn_mfma_f32_16x16x32_bf16(a[i], b, acc[i][nt], 0, 0, 0);
      }
    }
  }
#pragma unroll
  for (int i = 0; i < 2; i++)
#pragma unroll
    for (int nt = 0; nt < 4; nt++)
#pragma unroll
      for (int r = 0; r < 4; r++)
        G[(size_t)(m0 + wm * 32 + i * 16 + qd * 4 + r) * 128 + wn * 64 + nt * 16 + ln] =
            acc[i][nt][r];
}

// ---------------- persistent fused scan -------------------------------------
// 1024 threads (16 waves), 64 rows/block, grid 256 (1 block/CU forced by LDS).
// Runs all 11 steps; grid_barrier between steps. Body identical to round 7.
__global__ __launch_bounds__(1024, 4) void scan_persist(
    float* __restrict__ Ga, float* __restrict__ Gb,
    const u16* __restrict__ W1f, const u16* __restrict__ W2t,
    const float* __restrict__ b1, const float* __restrict__ b2,
    const float* __restrict__ fid, u16* __restrict__ Qout,
    unsigned* __restrict__ bar) {
  __shared__ u16 BUF[64 * 1024];  // 128KB
  __shared__ unsigned rmax[64];
  const int tid = threadIdx.x, lane = tid & 63, wv = tid >> 6;
  const int ln = lane & 15, qd = lane >> 4;
  const int r0 = blockIdx.x * 64;
  const u16* w2b = W2t + (size_t)wv * 64 * 128;  // this wave's 64-col W2t slice
  int n = 1;
  for (int s = 0; s < 11; s++, n <<= 1) {
    const bool last = (s == 10);
    const float* Gsrc = (s & 1) ? Gb : Ga;
    float* Gdst = (s & 1) ? Ga : Gb;
    if (tid < 64) rmax[tid] = 0u;
    // ---- P0: f = G1[gr-n]|fid + G2[gr] + b1 ; sincos -> S (swizzled)
    {
      const int r = tid >> 4, js = (tid & 15) << 2;
      const int gr = r0 + r, tl = gr & (T_DIM - 1);
      const float* g1p = (tl >= n) ? &Gsrc[(size_t)(gr - n) * 128 + js] : &fid[js];
      const float4 g1 = *(const float4*)g1p;
      const float4 g2 = *(const float4*)&Gsrc[(size_t)gr * 128 + 64 + js];
      const float4 bb = *(const float4*)&b1[js];
      float f[4] = {g1.x + g2.x + bb.x, g1.y + g2.y + bb.y,
                    g1.z + g2.z + bb.z, g1.w + g2.w + bb.w};
      alignas(8) u16 sn[4], cs[4];
#pragma unroll
      for (int c = 0; c < 4; c++) {
        float sv, cv;
        __sincosf(f[c], &sv, &cv);
        sn[c] = f2bf(sv);
        cs[c] = f2bf(cv);
      }
      const int u = js >> 3, half = (js >> 2) & 1, rx = r & 7;
      const int ps = (u ^ rx) & 7;
      const int pc = 8 | ps;
      *(uint2*)&BUF[r * 128 + ps * 8 + half * 4] = *(const uint2*)sn;
      *(uint2*)&BUF[r * 128 + pc * 8 + half * 4] = *(const uint2*)cs;
    }
    __syncthreads();
    // ---- P1: z2^T tiles via swapped MFMA operands. Wave owns 64 cols.
    f32x4 acc[4][4] = {};
#pragma unroll
    for (int ks = 0; ks < 4; ks++) {
      short8 af[4];
#pragma unroll
      for (int i = 0; i < 4; i++) {
        const int ar = i * 16 + ln;
        const int u = ks * 4 + qd;
        af[i] = *(const short8*)&BUF[ar * 128 + ((u & 8) | ((u ^ ar) & 7)) * 8];
      }
#pragma unroll
      for (int nt = 0; nt < 4; nt++) {
        const short8 b = *(const short8*)&w2b[(size_t)(nt * 16 + ln) * 128 + ks * 32 + qd * 8];
#pragma unroll
        for (int i = 0; i < 4; i++)
          acc[i][nt] = __builtin_amdgcn_mfma_f32_16x16x32_bf16(b, af[i], acc[i][nt], 0, 0, 0);
      }
    }
    // bias + per-row absmax
    float mx[4] = {0.f, 0.f, 0.f, 0.f};
#pragma unroll
    for (int nt = 0; nt < 4; nt++) {
      const float4 bb = *(const float4*)&b2[wv * 64 + nt * 16 + qd * 4];
      const float br4[4] = {bb.x, bb.y, bb.z, bb.w};
#pragma unroll
      for (int i = 0; i < 4; i++)
#pragma unroll
        for (int r = 0; r < 4; r++) {
          const float v = acc[i][nt][r] + br4[r];
          acc[i][nt][r] = v;
          mx[i] = fmaxf(mx[i], fabsf(v));
        }
    }
#pragma unroll
    for (int i = 0; i < 4; i++) {
      float v = mx[i];
      v = fmaxf(v, __shfl_xor(v, 16, 64));
      v = fmaxf(v, __shfl_xor(v, 32, 64));
      if (lane < 16) atomicMax(&rmax[i * 16 + lane], __float_as_uint(v));
    }
    __syncthreads();
    // ---- P2: normalize -> q-tile bf16 into BUF (8B vector writes)
    float inv[4];
#pragma unroll
    for (int i = 0; i < 4; i++)
      inv[i] = 1.0f / (__uint_as_float(rmax[i * 16 + ln]) + 1e-6f);
#pragma unroll
    for (int i = 0; i < 4; i++) {
      const int row = i * 16 + ln, rx = row & 7;
#pragma unroll
      for (int nt = 0; nt < 4; nt++) {
        const unsigned lo = (unsigned)f2bf(acc[i][nt][0] * inv[i]) |
                            ((unsigned)f2bf(acc[i][nt][1] * inv[i]) << 16);
        const unsigned hi = (unsigned)f2bf(acc[i][nt][2] * inv[i]) |
                            ((unsigned)f2bf(acc[i][nt][3] * inv[i]) << 16);
        const int unit = wv * 8 + nt * 2 + (qd >> 1);
        const int phys = (unit & ~7) | ((unit ^ rx) & 7);
        uint2 pv;
        pv.x = lo;
        pv.y = hi;
        *(uint2*)&BUF[row * 1024 + phys * 8 + (qd & 1) * 4] = pv;
      }
    }
    __syncthreads();
    if (last) {  // final step: deswizzle q-tile to Qout, done
#pragma unroll
      for (int it = 0; it < 8; it++) {
        const int idx = it * 1024 + tid;  // 8192 uint4
        const int row = idx >> 7, unit = idx & 127;
        const int phys = (unit & ~7) | ((unit ^ (row & 7)) & 7);
        *(uint4*)&Qout[(size_t)(r0 + row) * 1024 + unit * 8] =
            ((const uint4*)BUF)[row * 128 + phys];
      }
    } else {
      if (wv < 8) {  // G' = q @ W1f : 64x128 out, K=1024; 32x32 tile/wave
        const int wm2 = wv >> 2, wn2 = wv & 3;
        const u16* w1b = W1f + (size_t)(wn2 * 32) * 1024;
        f32x4 g[2][2] = {};
#pragma unroll
        for (int ks = 0; ks < 32; ks++) {
          short8 a[2], b[2];
#pragma unroll
          for (int t = 0; t < 2; t++) {
            const int row = wm2 * 32 + t * 16 + ln;
            const int u = ks * 4 + qd;
            const int phys = (u & ~7) | ((u ^ (row & 7)) & 7);
            a[t] = *(const short8*)&BUF[row * 1024 + phys * 8];
          }
#pragma unroll
          for (int c = 0; c < 2; c++)
            b[c] = *(const short8*)&w1b[(size_t)(c * 16 + ln) * 1024 + ks * 32 + qd * 8];
#pragma unroll
          for (int t = 0; t < 2; t++)
#pragma unroll
            for (int c = 0; c < 2; c++)
              g[t][c] = __builtin_amdgcn_mfma_f32_16x16x32_bf16(a[t], b[c], g[t][c], 0, 0, 0);
        }
#pragma unroll
        for (int t = 0; t < 2; t++)
#pragma unroll
          for (int c = 0; c < 2; c++)
#pragma unroll
            for (int r = 0; r < 4; r++)
              Gdst[(size_t)(r0 + wm2 * 32 + t * 16 + qd * 4 + r) * 128 +
                   wn2 * 32 + c * 16 + ln] = g[t][c][r];
      }
      grid_barrier(bar);
    }
  }
}

// ---------------- launch ----------------------------------------------------
extern "C" void kernel_launch(void* const* d_in, const int* in_sizes, int n_in,
                              void* d_out, int out_size, void* d_ws, size_t ws_size,
                              hipStream_t stream) {
  const float* x      = (const float*)d_in[0];
  const float* attn_W = (const float*)d_in[1];
  const float* attn_b = (const float*)d_in[2];
  const float* freq_W = (const float*)d_in[3];
  const float* freq_b = (const float*)d_in[4];
  const float* out_W  = (const float*)d_in[5];
  const float* out_b  = (const float*)d_in[6];
  const float* proj_W = (const float*)d_in[7];
  const float* proj_b = (const float*)d_in[8];
  const float* ident  = (const float*)d_in[9];
  float* out = (float*)d_out;

  const size_t RC = (size_t)R_ROWS * C_DIM;
  u16* Xb  = (u16*)d_ws;                     // 32MB
  u16* Qb  = Xb + RC;                        // 32MB
  u16* Vb  = Qb + RC;                        // 32MB
  u16* aWt = Vb + RC;                        // 4MB
  u16* pWt = aWt + (size_t)2048 * 1024;      // 2MB
  u16* w2t = pWt + (size_t)1024 * 1024;      // 256KB
  u16* w1f = w2t + (size_t)1024 * 128;       // 256KB
  float* Ga  = (float*)(w1f + (size_t)128 * 1024);  // 8MB
  float* Gb  = Ga + (size_t)R_ROWS * 128;           // 8MB
  float* fid = Gb + (size_t)R_ROWS * 128;           // 256B
  unsigned* bar = (unsigned*)(fid + 64);            // 8B

  // barrier state zero (self-restoring afterwards; memset covers first run)
  hipMemsetAsync(bar, 0, 8, stream);

  // prep
  cvt_bf16<<<8192, 256, 0, stream>>>(x, Xb, (int)(RC / 8));
  cvt_T<<<dim3(32, 64), 256, 0, stream>>>(attn_W, aWt, 1024, 2048);
  cvt_T<<<dim3(32, 32), 256, 0, stream>>>(proj_W, pWt, 1024, 1024);
  cvt_T<<<dim3(4, 32), 256, 0, stream>>>(out_W, w2t, 128, 1024);
  cvt_w1f<<<dim3(64, 2), 256, 0, stream>>>(freq_W, w1f);
  fid_kernel<<<1, 256, 0, stream>>>(ident, freq_W, fid);

  // q0, v
  gemm_qv_mfma<<<dim3(16, 128), 256, 0, stream>>>(Xb, aWt, attn_b, Qb, Vb);
  // G0 = q0 @ W1full
  g0_kernel<<<256, 256, 0, stream>>>(Qb, w1f, Ga);

  // persistent scan: all 11 steps in one dispatch; last writes q into Qb
  scan_persist<<<256, 1024, 0, stream>>>(Ga, Gb, w1f, w2t, freq_b, out_b, fid,
                                         Qb, bar);

  // Y = q*v ; out = Y @ proj_W + proj_b
  prod_bf16<<<8192, 256, 0, stream>>>(Qb, Vb, Xb, (int)(RC / 8));
  gemm_proj_mfma<<<dim3(8, 128), 256, 0, stream>>>(Xb, pWt, proj_b, out);
}

// Round 5
// 539.814 us; speedup vs baseline: 2.3228x; 2.3228x over previous
//
#include <hip/hip_runtime.h>
#include <hip/hip_bf16.h>
#include <math.h>

// SSMBlock: B=8, T=2048, C=1024, NF=64. R = 16384 rows.
// Round 9: revert to round-7 structure (11 scan dispatches; persistent-kernel
// grid barrier was a 3x regression: per-block device fences flush L2 256x per
// step). Change vs round 7: G' now uses ALL 16 waves (32r x 16c tile/wave,
// 2 MFMA tiles, 64 MFMA/wave) instead of 8 waves with 32x32 tiles.
// ws: Xb 32M | Qb 32M | Vb 32M | aWt 4M | pWt 2M | w2t/.w1f 512K | Ga/Gb 16M | fid

#define R_ROWS 16384
#define T_DIM  2048
#define C_DIM  1024

typedef unsigned short u16;
typedef __attribute__((ext_vector_type(8))) short short8;
typedef __attribute__((ext_vector_type(4))) float f32x4;

__device__ __forceinline__ u16 f2bf(float f) {
  union { float f; unsigned u; } v; v.f = f;
  unsigned r = v.u + 0x7fffu + ((v.u >> 16) & 1u);
  return (u16)(r >> 16);
}
__device__ __forceinline__ float bf2f(u16 h) {
  union { unsigned u; float f; } v; v.u = ((unsigned)h) << 16;
  return v.f;
}
__device__ __forceinline__ void gld16(const void* g, void* l) {
  __builtin_amdgcn_global_load_lds(
      (const __attribute__((address_space(1))) void*)g,
      (__attribute__((address_space(3))) void*)l, 16, 0, 0);
}

// ---------------- elementwise ----------------------------------------------
__global__ __launch_bounds__(256) void cvt_bf16(const float* __restrict__ in,
                                                u16* __restrict__ out, int n8) {
  const int i = blockIdx.x * 256 + threadIdx.x;
  if (i >= n8) return;
  const float4 a = ((const float4*)in)[2 * i];
  const float4 b = ((const float4*)in)[2 * i + 1];
  alignas(16) u16 t[8] = {f2bf(a.x), f2bf(a.y), f2bf(a.z), f2bf(a.w),
                          f2bf(b.x), f2bf(b.y), f2bf(b.z), f2bf(b.w)};
  ((uint4*)out)[i] = *(const uint4*)t;
}

__global__ __launch_bounds__(256) void prod_bf16(const u16* __restrict__ a,
                                                 const u16* __restrict__ b,
                                                 u16* __restrict__ o, int n8) {
  const int i = blockIdx.x * 256 + threadIdx.x;
  if (i >= n8) return;
  uint4 ua = ((const uint4*)a)[i], ub = ((const uint4*)b)[i];
  const u16* pa = (const u16*)&ua;
  const u16* pb = (const u16*)&ub;
  alignas(16) u16 t[8];
#pragma unroll
  for (int c = 0; c < 8; c++) t[c] = f2bf(bf2f(pa[c]) * bf2f(pb[c]));
  ((uint4*)o)[i] = *(const uint4*)t;
}

// ---------------- weight prep ----------------------------------------------
__global__ __launch_bounds__(256) void cvt_T(const float* __restrict__ W,
                                             u16* __restrict__ Wt, int K, int N) {
  __shared__ float t[32][33];
  const int k0 = blockIdx.x * 32, n0 = blockIdx.y * 32;
  const int tx = threadIdx.x & 31, ty = threadIdx.x >> 5;
#pragma unroll
  for (int i = 0; i < 32; i += 8)
    t[ty + i][tx] = W[(size_t)(k0 + ty + i) * N + n0 + tx];
  __syncthreads();
#pragma unroll
  for (int i = 0; i < 32; i += 8)
    Wt[(size_t)(n0 + ty + i) * K + k0 + tx] = f2bf(t[tx][ty + i]);
}

// freq_W [2048][64] -> W1f [128][1024]: rows 0..63 = top (k<1024), 64..127 = bot
__global__ __launch_bounds__(256) void cvt_w1f(const float* __restrict__ W,
                                               u16* __restrict__ W1f) {
  __shared__ float t[32][33];
  const int k0 = blockIdx.x * 32, n0 = blockIdx.y * 32;
  const int tx = threadIdx.x & 31, ty = threadIdx.x >> 5;
#pragma unroll
  for (int i = 0; i < 32; i += 8)
    t[ty + i][tx] = W[(size_t)(k0 + ty + i) * 64 + n0 + tx];
  __syncthreads();
#pragma unroll
  for (int i = 0; i < 32; i += 8) {
    const int k = k0 + tx;
    const int row = (n0 + ty + i) + ((k >= 1024) ? 64 : 0);
    W1f[(size_t)row * 1024 + (k & 1023)] = f2bf(t[tx][ty + i]);
  }
}

// fid[j] = sum_{k<1024} identity[k] * freq_W[k][j]
__global__ __launch_bounds__(256) void fid_kernel(const float* __restrict__ ident,
                                                  const float* __restrict__ W,
                                                  float* __restrict__ fid) {
  __shared__ float red[256];
  const int tid = threadIdx.x;
  const int j = tid >> 2, part = tid & 3;
  float s = 0.f;
  for (int k = part * 256; k < part * 256 + 256; k++)
    s += ident[k] * W[(size_t)k * 64 + j];
  red[tid] = s;
  __syncthreads();
  if (part == 0) fid[j] = red[tid] + red[tid + 1] + red[tid + 2] + red[tid + 3];
}

// ---------------- big GEMMs (m97-style + XCD swizzle) -----------------------
#define GEMM_KLOOP(Aptr, Bptr)                                                 \
  const int tid = threadIdx.x, lane = tid & 63, w = tid >> 6;                  \
  const int ln = lane & 15, qd = lane >> 4;                                    \
  const int wm = w & 1, wn = w >> 1;                                           \
  const int nbx = gridDim.x;                                                   \
  const int bid0 = blockIdx.y * nbx + blockIdx.x;                              \
  const int nwg = nbx * gridDim.y;                                             \
  const int bid = (bid0 & 7) * (nwg >> 3) + (bid0 >> 3);                       \
  const int n0 = (bid % nbx) * 128, m0 = (bid / nbx) * 128;                    \
  const int srow = w * 32 + (lane >> 3);                                       \
  const int sl = (lane & 7) ^ ((lane >> 3) & 7);                               \
  const int scol = sl * 8;                                                     \
  f32x4 acc[4][4] = {};                                                        \
  for (int kt = 0; kt < 1024; kt += 64) {                                      \
    __syncthreads();                                                           \
    _Pragma("unroll") for (int j = 0; j < 4; j++) {                            \
      gld16(&Aptr[(size_t)(m0 + srow + j * 8) * 1024 + kt + scol],             \
            &As[(w * 32 + j * 8) * 64]);                                       \
      gld16(&Bptr[(size_t)(n0 + srow + j * 8) * 1024 + kt + scol],             \
            &Bs[(w * 32 + j * 8) * 64]);                                       \
    }                                                                          \
    __syncthreads();                                                           \
    _Pragma("unroll") for (int ks = 0; ks < 2; ks++) {                         \
      short8 af[4], bf_[4];                                                    \
      _Pragma("unroll") for (int i = 0; i < 4; i++) {                          \
        const int ar = wm * 64 + i * 16 + ln;                                  \
        af[i] = *(const short8*)&As[ar * 64 + ((ks * 4 + qd) ^ (ar & 7)) * 8]; \
      }                                                                        \
      _Pragma("unroll") for (int j = 0; j < 4; j++) {                          \
        const int br = wn * 64 + j * 16 + ln;                                  \
        bf_[j] = *(const short8*)&Bs[br * 64 + ((ks * 4 + qd) ^ (br & 7)) * 8];\
      }                                                                        \
      _Pragma("unroll") for (int i = 0; i < 4; i++)                            \
      _Pragma("unroll") for (int j = 0; j < 4; j++)                            \
        acc[i][j] = __builtin_amdgcn_mfma_f32_16x16x32_bf16(af[i], bf_[j],     \
                                                            acc[i][j], 0, 0, 0);\
    }                                                                          \
  }                                                                            \
  __syncthreads();

__global__ __launch_bounds__(256) void gemm_qv_mfma(
    const u16* __restrict__ A, const u16* __restrict__ Bt,
    const float* __restrict__ bias, u16* __restrict__ Qb, u16* __restrict__ Vb) {
  __shared__ u16 S[16384];
  u16* As = S;
  u16* Bs = S + 8192;
  GEMM_KLOOP(A, Bt)
#pragma unroll
  for (int j = 0; j < 4; j++) {
    const int col = wn * 64 + j * 16 + ln;
    const float bv = bias[n0 + col];
#pragma unroll
    for (int i = 0; i < 4; i++)
#pragma unroll
      for (int r = 0; r < 4; r++)
        S[(wm * 64 + i * 16 + qd * 4 + r) * 128 + col] = f2bf(acc[i][j][r] + bv);
  }
  __syncthreads();
  const bool isQ = (n0 < 1024);
  u16* dst = isQ ? Qb : Vb;
  const int nb = isQ ? n0 : n0 - 1024;
#pragma unroll
  for (int it = 0; it < 8; it++) {
    const int idx = it * 256 + tid;
    const int row = idx >> 4, seg = idx & 15;
    *(uint4*)&dst[(size_t)(m0 + row) * 1024 + nb + seg * 8] = ((const uint4*)S)[idx];
  }
}

__global__ __launch_bounds__(256) void gemm_proj_mfma(
    const u16* __restrict__ A, const u16* __restrict__ Bt,
    const float* __restrict__ bias, float* __restrict__ OUT) {
  __shared__ u16 S[16384];
  u16* As = S;
  u16* Bs = S + 8192;
  GEMM_KLOOP(A, Bt)
  float* Csf = (float*)S;
#pragma unroll
  for (int p = 0; p < 2; p++) {
    if (wm == p) {
#pragma unroll
      for (int j = 0; j < 4; j++) {
        const int col = wn * 64 + j * 16 + ln;
        const float bv = bias[n0 + col];
#pragma unroll
        for (int i = 0; i < 4; i++)
#pragma unroll
          for (int r = 0; r < 4; r++)
            Csf[(i * 16 + qd * 4 + r) * 128 + col] = acc[i][j][r] + bv;
      }
    }
    __syncthreads();
#pragma unroll
    for (int it = 0; it < 8; it++) {
      const int idx = it * 256 + tid;
      const int row = idx >> 5, seg = idx & 31;
      *(uint4*)&OUT[(size_t)(m0 + p * 64 + row) * 1024 + n0 + seg * 4] =
          ((const uint4*)Csf)[idx];
    }
    __syncthreads();
  }
}

// ---------------- G0 = q @ W1full : M=16384 N=128 K=1024 --------------------
// 256 threads (4 waves 2m x 2n), m-tile 64, grid 256.
__global__ __launch_bounds__(256) void g0_kernel(const u16* __restrict__ Qb,
                                                 const u16* __restrict__ W1f,
                                                 float* __restrict__ G) {
  __shared__ u16 As[64 * 64];  // 8KB
  const int tid = threadIdx.x, lane = tid & 63, wv = tid >> 6;
  const int ln = lane & 15, qd = lane >> 4;
  const int wm = wv >> 1, wn = wv & 1;
  const int m0 = blockIdx.x * 64;
  const int srow = wv * 16 + (lane >> 3);
  const int scol = ((lane & 7) ^ ((lane >> 3) & 7)) * 8;
  f32x4 acc[2][4] = {};
  for (int kt = 0; kt < 1024; kt += 64) {
    __syncthreads();
#pragma unroll
    for (int j = 0; j < 2; j++)
      gld16(&Qb[(size_t)(m0 + srow + j * 8) * 1024 + kt + scol],
            &As[(wv * 16 + j * 8) * 64]);
    __syncthreads();
#pragma unroll
    for (int ks = 0; ks < 2; ks++) {
      short8 a[2];
#pragma unroll
      for (int i = 0; i < 2; i++) {
        const int ar = wm * 32 + i * 16 + ln;
        a[i] = *(const short8*)&As[ar * 64 + ((ks * 4 + qd) ^ (ar & 7)) * 8];
      }
#pragma unroll
      for (int nt = 0; nt < 4; nt++) {
        const short8 b = *(const short8*)&W1f[(size_t)(wn * 64 + nt * 16 + ln) * 1024 +
                                              kt + ks * 32 + qd * 8];
#pragma unroll
        for (int i = 0; i < 2; i++)
          acc[i][nt] = __builtin_amdgcn_mfma_f32_16x16x32_bf16(a[i], b, acc[i][nt], 0, 0, 0);
      }
    }
  }
#pragma unroll
  for (int i = 0; i < 2; i++)
#pragma unroll
    for (int nt = 0; nt < 4; nt++)
#pragma unroll
      for (int r = 0; r < 4; r++)
        G[(size_t)(m0 + wm * 32 + i * 16 + qd * 4 + r) * 128 + wn * 64 + nt * 16 + ln] =
            acc[i][nt][r];
}

// ---------------- fused scan step -------------------------------------------
// 1024 threads (16 waves, 4 waves/SIMD), 64 rows/block, grid 256 (1 block/CU).
// flags: 1 = write q to Qout (last step), 2 = compute Gdst (all but last).
// z2 TRANSPOSED via swapped MFMA operands: acc[i][nt] holds
// z2[row=i*16+ln][col=wv*64+nt*16+qd*4+r]. Wave wv owns a distinct 64-col
// slice of W2t (256KB/block total, no dup). BUF: phase A = S (64 x 128 bf16,
// rowstride 128, 8-col-unit XOR swizzle); phase B = q-tile (64 x 1024 bf16,
// rowstride 1024, 16B-unit XOR swizzle phys = (u&~7)|((u^(row&7))&7)).
// G' uses ALL 16 waves: 32r x 16c tile/wave (2 MFMA tiles, 64 MFMA/wave).
__global__ __launch_bounds__(1024, 4) void scan_fused(
    const float* __restrict__ Gsrc, float* __restrict__ Gdst,
    const u16* __restrict__ W1f, const u16* __restrict__ W2t,
    const float* __restrict__ b1, const float* __restrict__ b2,
    const float* __restrict__ fid, u16* __restrict__ Qout, int n, int flags) {
  __shared__ u16 BUF[64 * 1024];  // 128KB
  __shared__ unsigned rmax[64];
  const int tid = threadIdx.x, lane = tid & 63, wv = tid >> 6;
  const int ln = lane & 15, qd = lane >> 4;
  const int r0 = blockIdx.x * 64;
  if (tid < 64) rmax[tid] = 0u;
  // ---- P0: f = G1[gr-n]|fid + G2[gr] + b1 ; sincos -> S (swizzled).
  // 1024 threads: 4 f-cols each.
  {
    const int r = tid >> 4, js = (tid & 15) << 2;
    const int gr = r0 + r, tl = gr & (T_DIM - 1);
    const float* g1p = (tl >= n) ? &Gsrc[(size_t)(gr - n) * 128 + js] : &fid[js];
    const float4 g1 = *(const float4*)g1p;
    const float4 g2 = *(const float4*)&Gsrc[(size_t)gr * 128 + 64 + js];
    const float4 bb = *(const float4*)&b1[js];
    float f[4] = {g1.x + g2.x + bb.x, g1.y + g2.y + bb.y,
                  g1.z + g2.z + bb.z, g1.w + g2.w + bb.w};
    alignas(8) u16 sn[4], cs[4];
#pragma unroll
    for (int c = 0; c < 4; c++) {
      float sv, cv;
      __sincosf(f[c], &sv, &cv);
      sn[c] = f2bf(sv);
      cs[c] = f2bf(cv);
    }
    const int u = js >> 3, half = (js >> 2) & 1, rx = r & 7;
    const int ps = (u ^ rx) & 7;            // sin unit in [0,8)
    const int pc = 8 | ps;                  // cos unit in [8,16)
    *(uint2*)&BUF[r * 128 + ps * 8 + half * 4] = *(const uint2*)sn;
    *(uint2*)&BUF[r * 128 + pc * 8 + half * 4] = *(const uint2*)cs;
  }
  __syncthreads();
  // ---- P1: z2^T tiles via swapped MFMA operands. Wave owns 64 cols.
  const u16* w2b = W2t + (size_t)wv * 64 * 128;
  f32x4 acc[4][4] = {};
#pragma unroll
  for (int ks = 0; ks < 4; ks++) {
    short8 af[4];
#pragma unroll
    for (int i = 0; i < 4; i++) {
      const int ar = i * 16 + ln;
      const int u = ks * 4 + qd;
      af[i] = *(const short8*)&BUF[ar * 128 + ((u & 8) | ((u ^ ar) & 7)) * 8];
    }
#pragma unroll
    for (int nt = 0; nt < 4; nt++) {
      const short8 b = *(const short8*)&w2b[(size_t)(nt * 16 + ln) * 128 + ks * 32 + qd * 8];
#pragma unroll
      for (int i = 0; i < 4; i++)
        acc[i][nt] = __builtin_amdgcn_mfma_f32_16x16x32_bf16(b, af[i], acc[i][nt], 0, 0, 0);
    }
  }
  // bias + per-row absmax (row = i*16+ln; qd groups hold disjoint col sets)
  float mx[4] = {0.f, 0.f, 0.f, 0.f};
#pragma unroll
  for (int nt = 0; nt < 4; nt++) {
    const float4 bb = *(const float4*)&b2[wv * 64 + nt * 16 + qd * 4];
    const float br4[4] = {bb.x, bb.y, bb.z, bb.w};
#pragma unroll
    for (int i = 0; i < 4; i++)
#pragma unroll
      for (int r = 0; r < 4; r++) {
        const float v = acc[i][nt][r] + br4[r];
        acc[i][nt][r] = v;
        mx[i] = fmaxf(mx[i], fabsf(v));
      }
  }
#pragma unroll
  for (int i = 0; i < 4; i++) {
    float v = mx[i];
    v = fmaxf(v, __shfl_xor(v, 16, 64));
    v = fmaxf(v, __shfl_xor(v, 32, 64));
    if (lane < 16) atomicMax(&rmax[i * 16 + lane], __float_as_uint(v));
  }
  __syncthreads();  // rmax complete; all S reads retired (BUF reuse below)
  // ---- P2: normalize -> q-tile bf16 into BUF (8B vector writes)
  float inv[4];
#pragma unroll
  for (int i = 0; i < 4; i++)
    inv[i] = 1.0f / (__uint_as_float(rmax[i * 16 + ln]) + 1e-6f);
#pragma unroll
  for (int i = 0; i < 4; i++) {
    const int row = i * 16 + ln, rx = row & 7;
#pragma unroll
    for (int nt = 0; nt < 4; nt++) {
      const unsigned lo = (unsigned)f2bf(acc[i][nt][0] * inv[i]) |
                          ((unsigned)f2bf(acc[i][nt][1] * inv[i]) << 16);
      const unsigned hi = (unsigned)f2bf(acc[i][nt][2] * inv[i]) |
                          ((unsigned)f2bf(acc[i][nt][3] * inv[i]) << 16);
      const int unit = wv * 8 + nt * 2 + (qd >> 1);
      const int phys = (unit & ~7) | ((unit ^ rx) & 7);
      uint2 pv;
      pv.x = lo;
      pv.y = hi;
      *(uint2*)&BUF[row * 1024 + phys * 8 + (qd & 1) * 4] = pv;
    }
  }
  __syncthreads();
  if (flags & 1) {  // last step: deswizzle q-tile to Qout
#pragma unroll
    for (int it = 0; it < 8; it++) {
      const int idx = it * 1024 + tid;  // 8192 uint4
      const int row = idx >> 7, unit = idx & 127;
      const int phys = (unit & ~7) | ((unit ^ (row & 7)) & 7);
      *(uint4*)&Qout[(size_t)(r0 + row) * 1024 + unit * 8] =
          ((const uint4*)BUF)[row * 128 + phys];
    }
  }
  if (flags & 2) {  // G' = q @ W1f : 64x128 out, K=1024; 16 waves, 32r x 16c
    const int wm2 = wv >> 3, wn2 = wv & 7;
    const u16* w1b = W1f + (size_t)(wn2 * 16) * 1024;
    f32x4 g[2] = {};
    for (int ks = 0; ks < 32; ks++) {
      short8 a[2];
#pragma unroll
      for (int t = 0; t < 2; t++) {
        const int row = wm2 * 32 + t * 16 + ln;
        const int u = ks * 4 + qd;
        const int phys = (u & ~7) | ((u ^ (row & 7)) & 7);
        a[t] = *(const short8*)&BUF[row * 1024 + phys * 8];
      }
      const short8 b = *(const short8*)&w1b[(size_t)ln * 1024 + ks * 32 + qd * 8];
#pragma unroll
      for (int t = 0; t < 2; t++)
        g[t] = __builtin_amdgcn_mfma_f32_16x16x32_bf16(a[t], b, g[t], 0, 0, 0);
    }
#pragma unroll
    for (int t = 0; t < 2; t++)
#pragma unroll
      for (int r = 0; r < 4; r++)
        Gdst[(size_t)(r0 + wm2 * 32 + t * 16 + qd * 4 + r) * 128 + wn2 * 16 + ln] =
            g[t][r];
  }
}

// ---------------- launch ----------------------------------------------------
extern "C" void kernel_launch(void* const* d_in, const int* in_sizes, int n_in,
                              void* d_out, int out_size, void* d_ws, size_t ws_size,
                              hipStream_t stream) {
  const float* x      = (const float*)d_in[0];
  const float* attn_W = (const float*)d_in[1];
  const float* attn_b = (const float*)d_in[2];
  const float* freq_W = (const float*)d_in[3];
  const float* freq_b = (const float*)d_in[4];
  const float* out_W  = (const float*)d_in[5];
  const float* out_b  = (const float*)d_in[6];
  const float* proj_W = (const float*)d_in[7];
  const float* proj_b = (const float*)d_in[8];
  const float* ident  = (const float*)d_in[9];
  float* out = (float*)d_out;

  const size_t RC = (size_t)R_ROWS * C_DIM;
  u16* Xb  = (u16*)d_ws;                     // 32MB
  u16* Qb  = Xb + RC;                        // 32MB
  u16* Vb  = Qb + RC;                        // 32MB
  u16* aWt = Vb + RC;                        // 4MB
  u16* pWt = aWt + (size_t)2048 * 1024;      // 2MB
  u16* w2t = pWt + (size_t)1024 * 1024;      // 256KB
  u16* w1f = w2t + (size_t)1024 * 128;       // 256KB
  float* Ga  = (float*)(w1f + (size_t)128 * 1024);  // 8MB
  float* Gb  = Ga + (size_t)R_ROWS * 128;           // 8MB
  float* fid = Gb + (size_t)R_ROWS * 128;           // 256B

  // prep
  cvt_bf16<<<8192, 256, 0, stream>>>(x, Xb, (int)(RC / 8));
  cvt_T<<<dim3(32, 64), 256, 0, stream>>>(attn_W, aWt, 1024, 2048);
  cvt_T<<<dim3(32, 32), 256, 0, stream>>>(proj_W, pWt, 1024, 1024);
  cvt_T<<<dim3(4, 32), 256, 0, stream>>>(out_W, w2t, 128, 1024);
  cvt_w1f<<<dim3(64, 2), 256, 0, stream>>>(freq_W, w1f);
  fid_kernel<<<1, 256, 0, stream>>>(ident, freq_W, fid);

  // q0, v
  gemm_qv_mfma<<<dim3(16, 128), 256, 0, stream>>>(Xb, aWt, attn_b, Qb, Vb);
  // G0 = q0 @ W1full
  g0_kernel<<<256, 256, 0, stream>>>(Qb, w1f, Ga);

  // 11 fused steps over G; last writes q into Qb (dead after g0)
  float* gs = Ga;
  float* gd = Gb;
  for (int n = 1; n < T_DIM; n <<= 1) {
    const int last = (n == 1024);
    scan_fused<<<256, 1024, 0, stream>>>(gs, gd, w1f, w2t, freq_b, out_b, fid,
                                         Qb, n, last ? 1 : 2);
    float* t = gs; gs = gd; gd = t;
  }

  // Y = q*v ; out = Y @ proj_W + proj_b
  prod_bf16<<<8192, 256, 0, stream>>>(Qb, Vb, Xb, (int)(RC / 8));
  gemm_proj_mfma<<<dim3(8, 128), 256, 0, stream>>>(Xb, pWt, proj_b, out);
}

// Round 6
// 440.567 us; speedup vs baseline: 2.8460x; 1.2253x over previous
//
#include <hip/hip_runtime.h>
#include <hip/hip_bf16.h>
#include <math.h>

// SSMBlock: B=8, T=2048, C=1024, NF=64. R = 16384 rows.
// Round 10: algebraic restructure of the scan step. G' = q @ W1f is replaced by
// G' = (S @ W21t^T + c1) * inv_rowmax, with W21t = W1f x W2^T (128x128 bf16)
// and c1 = W1f x b2 precomputed once. Kills the K=1024 G' GEMM (1024->128 MFMA
// per block), the 512KB W1f reads (->32KB), and the whole q-tile LDS round
// trip (last step stores q direct from registers). LDS 128KB -> 17KB.
// P0 (sincos), P1 (z2^T K=128 MFMA, row absmax) unchanged from round 7/9.
// ws: Xb 32M | Qb 32M | Vb 32M | aWt 4M | pWt 2M | w2t/.w1f 512K | Ga/Gb 16M |
//     fid 256B | c1 512B | W21t 32K

#define R_ROWS 16384
#define T_DIM  2048
#define C_DIM  1024

typedef unsigned short u16;
typedef __attribute__((ext_vector_type(8))) short short8;
typedef __attribute__((ext_vector_type(4))) float f32x4;

__device__ __forceinline__ u16 f2bf(float f) {
  union { float f; unsigned u; } v; v.f = f;
  unsigned r = v.u + 0x7fffu + ((v.u >> 16) & 1u);
  return (u16)(r >> 16);
}
__device__ __forceinline__ float bf2f(u16 h) {
  union { unsigned u; float f; } v; v.u = ((unsigned)h) << 16;
  return v.f;
}
__device__ __forceinline__ void gld16(const void* g, void* l) {
  __builtin_amdgcn_global_load_lds(
      (const __attribute__((address_space(1))) void*)g,
      (__attribute__((address_space(3))) void*)l, 16, 0, 0);
}

// ---------------- elementwise ----------------------------------------------
__global__ __launch_bounds__(256) void cvt_bf16(const float* __restrict__ in,
                                                u16* __restrict__ out, int n8) {
  const int i = blockIdx.x * 256 + threadIdx.x;
  if (i >= n8) return;
  const float4 a = ((const float4*)in)[2 * i];
  const float4 b = ((const float4*)in)[2 * i + 1];
  alignas(16) u16 t[8] = {f2bf(a.x), f2bf(a.y), f2bf(a.z), f2bf(a.w),
                          f2bf(b.x), f2bf(b.y), f2bf(b.z), f2bf(b.w)};
  ((uint4*)out)[i] = *(const uint4*)t;
}

__global__ __launch_bounds__(256) void prod_bf16(const u16* __restrict__ a,
                                                 const u16* __restrict__ b,
                                                 u16* __restrict__ o, int n8) {
  const int i = blockIdx.x * 256 + threadIdx.x;
  if (i >= n8) return;
  uint4 ua = ((const uint4*)a)[i], ub = ((const uint4*)b)[i];
  const u16* pa = (const u16*)&ua;
  const u16* pb = (const u16*)&ub;
  alignas(16) u16 t[8];
#pragma unroll
  for (int c = 0; c < 8; c++) t[c] = f2bf(bf2f(pa[c]) * bf2f(pb[c]));
  ((uint4*)o)[i] = *(const uint4*)t;
}

// ---------------- weight prep ----------------------------------------------
__global__ __launch_bounds__(256) void cvt_T(const float* __restrict__ W,
                                             u16* __restrict__ Wt, int K, int N) {
  __shared__ float t[32][33];
  const int k0 = blockIdx.x * 32, n0 = blockIdx.y * 32;
  const int tx = threadIdx.x & 31, ty = threadIdx.x >> 5;
#pragma unroll
  for (int i = 0; i < 32; i += 8)
    t[ty + i][tx] = W[(size_t)(k0 + ty + i) * N + n0 + tx];
  __syncthreads();
#pragma unroll
  for (int i = 0; i < 32; i += 8)
    Wt[(size_t)(n0 + ty + i) * K + k0 + tx] = f2bf(t[tx][ty + i]);
}

// freq_W [2048][64] -> W1f [128][1024]: rows 0..63 = top (k<1024), 64..127 = bot
__global__ __launch_bounds__(256) void cvt_w1f(const float* __restrict__ W,
                                               u16* __restrict__ W1f) {
  __shared__ float t[32][33];
  const int k0 = blockIdx.x * 32, n0 = blockIdx.y * 32;
  const int tx = threadIdx.x & 31, ty = threadIdx.x >> 5;
#pragma unroll
  for (int i = 0; i < 32; i += 8)
    t[ty + i][tx] = W[(size_t)(k0 + ty + i) * 64 + n0 + tx];
  __syncthreads();
#pragma unroll
  for (int i = 0; i < 32; i += 8) {
    const int k = k0 + tx;
    const int row = (n0 + ty + i) + ((k >= 1024) ? 64 : 0);
    W1f[(size_t)row * 1024 + (k & 1023)] = f2bf(t[tx][ty + i]);
  }
}

// fid[j] = sum_{k<1024} identity[k] * freq_W[k][j]
__global__ __launch_bounds__(256) void fid_kernel(const float* __restrict__ ident,
                                                  const float* __restrict__ W,
                                                  float* __restrict__ fid) {
  __shared__ float red[256];
  const int tid = threadIdx.x;
  const int j = tid >> 2, part = tid & 3;
  float s = 0.f;
  for (int k = part * 256; k < part * 256 + 256; k++)
    s += ident[k] * W[(size_t)k * 64 + j];
  red[tid] = s;
  __syncthreads();
  if (part == 0) fid[j] = red[tid] + red[tid + 1] + red[tid + 2] + red[tid + 3];
}

// W21t[j][s] = sum_c out_W[s][c] * W1f[j][c]  (j,s in [0,128), c in [0,1024))
// c1[j]     = sum_c out_b[c]  * W1f[j][c]
__global__ __launch_bounds__(256) void w21_kernel(const float* __restrict__ outW,
                                                  const float* __restrict__ outb,
                                                  const u16* __restrict__ w1f,
                                                  u16* __restrict__ W21t,
                                                  float* __restrict__ c1) {
  __shared__ float red[256];
  const int j = blockIdx.x, tid = threadIdx.x;
  const int s = tid >> 1, part = tid & 1;
  const u16* wrow = w1f + (size_t)j * 1024;
  float acc = 0.f;
  for (int c = part * 512; c < part * 512 + 512; c++)
    acc += outW[(size_t)s * 1024 + c] * bf2f(wrow[c]);
  red[tid] = acc;
  __syncthreads();
  if (part == 0) W21t[(size_t)j * 128 + s] = f2bf(red[2 * s] + red[2 * s + 1]);
  float cb = 0.f;
  if (tid < 128)
    for (int c = tid * 8; c < tid * 8 + 8; c++) cb += outb[c] * bf2f(wrow[c]);
  __syncthreads();
  red[tid] = (tid < 128) ? cb : 0.f;
  __syncthreads();
  if (tid < 64) red[tid] += red[tid + 64];
  __syncthreads();
  if (tid == 0) {
    float v = 0.f;
    for (int k2 = 0; k2 < 64; k2++) v += red[k2];
    c1[j] = v;
  }
}

// ---------------- big GEMMs (m97-style + XCD swizzle) -----------------------
#define GEMM_KLOOP(Aptr, Bptr)                                                 \
  const int tid = threadIdx.x, lane = tid & 63, w = tid >> 6;                  \
  const int ln = lane & 15, qd = lane >> 4;                                    \
  const int wm = w & 1, wn = w >> 1;                                           \
  const int nbx = gridDim.x;                                                   \
  const int bid0 = blockIdx.y * nbx + blockIdx.x;                              \
  const int nwg = nbx * gridDim.y;                                             \
  const int bid = (bid0 & 7) * (nwg >> 3) + (bid0 >> 3);                       \
  const int n0 = (bid % nbx) * 128, m0 = (bid / nbx) * 128;                    \
  const int srow = w * 32 + (lane >> 3);                                       \
  const int sl = (lane & 7) ^ ((lane >> 3) & 7);                               \
  const int scol = sl * 8;                                                     \
  f32x4 acc[4][4] = {};                                                        \
  for (int kt = 0; kt < 1024; kt += 64) {                                      \
    __syncthreads();                                                           \
    _Pragma("unroll") for (int j = 0; j < 4; j++) {                            \
      gld16(&Aptr[(size_t)(m0 + srow + j * 8) * 1024 + kt + scol],             \
            &As[(w * 32 + j * 8) * 64]);                                       \
      gld16(&Bptr[(size_t)(n0 + srow + j * 8) * 1024 + kt + scol],             \
            &Bs[(w * 32 + j * 8) * 64]);                                       \
    }                                                                          \
    __syncthreads();                                                           \
    _Pragma("unroll") for (int ks = 0; ks < 2; ks++) {                         \
      short8 af[4], bf_[4];                                                    \
      _Pragma("unroll") for (int i = 0; i < 4; i++) {                          \
        const int ar = wm * 64 + i * 16 + ln;                                  \
        af[i] = *(const short8*)&As[ar * 64 + ((ks * 4 + qd) ^ (ar & 7)) * 8]; \
      }                                                                        \
      _Pragma("unroll") for (int j = 0; j < 4; j++) {                          \
        const int br = wn * 64 + j * 16 + ln;                                  \
        bf_[j] = *(const short8*)&Bs[br * 64 + ((ks * 4 + qd) ^ (br & 7)) * 8];\
      }                                                                        \
      _Pragma("unroll") for (int i = 0; i < 4; i++)                            \
      _Pragma("unroll") for (int j = 0; j < 4; j++)                            \
        acc[i][j] = __builtin_amdgcn_mfma_f32_16x16x32_bf16(af[i], bf_[j],     \
                                                            acc[i][j], 0, 0, 0);\
    }                                                                          \
  }                                                                            \
  __syncthreads();

__global__ __launch_bounds__(256) void gemm_qv_mfma(
    const u16* __restrict__ A, const u16* __restrict__ Bt,
    const float* __restrict__ bias, u16* __restrict__ Qb, u16* __restrict__ Vb) {
  __shared__ u16 S[16384];
  u16* As = S;
  u16* Bs = S + 8192;
  GEMM_KLOOP(A, Bt)
#pragma unroll
  for (int j = 0; j < 4; j++) {
    const int col = wn * 64 + j * 16 + ln;
    const float bv = bias[n0 + col];
#pragma unroll
    for (int i = 0; i < 4; i++)
#pragma unroll
      for (int r = 0; r < 4; r++)
        S[(wm * 64 + i * 16 + qd * 4 + r) * 128 + col] = f2bf(acc[i][j][r] + bv);
  }
  __syncthreads();
  const bool isQ = (n0 < 1024);
  u16* dst = isQ ? Qb : Vb;
  const int nb = isQ ? n0 : n0 - 1024;
#pragma unroll
  for (int it = 0; it < 8; it++) {
    const int idx = it * 256 + tid;
    const int row = idx >> 4, seg = idx & 15;
    *(uint4*)&dst[(size_t)(m0 + row) * 1024 + nb + seg * 8] = ((const uint4*)S)[idx];
  }
}

__global__ __launch_bounds__(256) void gemm_proj_mfma(
    const u16* __restrict__ A, const u16* __restrict__ Bt,
    const float* __restrict__ bias, float* __restrict__ OUT) {
  __shared__ u16 S[16384];
  u16* As = S;
  u16* Bs = S + 8192;
  GEMM_KLOOP(A, Bt)
  float* Csf = (float*)S;
#pragma unroll
  for (int p = 0; p < 2; p++) {
    if (wm == p) {
#pragma unroll
      for (int j = 0; j < 4; j++) {
        const int col = wn * 64 + j * 16 + ln;
        const float bv = bias[n0 + col];
#pragma unroll
        for (int i = 0; i < 4; i++)
#pragma unroll
          for (int r = 0; r < 4; r++)
            Csf[(i * 16 + qd * 4 + r) * 128 + col] = acc[i][j][r] + bv;
      }
    }
    __syncthreads();
#pragma unroll
    for (int it = 0; it < 8; it++) {
      const int idx = it * 256 + tid;
      const int row = idx >> 5, seg = idx & 31;
      *(uint4*)&OUT[(size_t)(m0 + p * 64 + row) * 1024 + n0 + seg * 4] =
          ((const uint4*)Csf)[idx];
    }
    __syncthreads();
  }
}

// ---------------- G0 = q @ W1full : M=16384 N=128 K=1024 --------------------
__global__ __launch_bounds__(256) void g0_kernel(const u16* __restrict__ Qb,
                                                 const u16* __restrict__ W1f,
                                                 float* __restrict__ G) {
  __shared__ u16 As[64 * 64];  // 8KB
  const int tid = threadIdx.x, lane = tid & 63, wv = tid >> 6;
  const int ln = lane & 15, qd = lane >> 4;
  const int wm = wv >> 1, wn = wv & 1;
  const int m0 = blockIdx.x * 64;
  const int srow = wv * 16 + (lane >> 3);
  const int scol = ((lane & 7) ^ ((lane >> 3) & 7)) * 8;
  f32x4 acc[2][4] = {};
  for (int kt = 0; kt < 1024; kt += 64) {
    __syncthreads();
#pragma unroll
    for (int j = 0; j < 2; j++)
      gld16(&Qb[(size_t)(m0 + srow + j * 8) * 1024 + kt + scol],
            &As[(wv * 16 + j * 8) * 64]);
    __syncthreads();
#pragma unroll
    for (int ks = 0; ks < 2; ks++) {
      short8 a[2];
#pragma unroll
      for (int i = 0; i < 2; i++) {
        const int ar = wm * 32 + i * 16 + ln;
        a[i] = *(const short8*)&As[ar * 64 + ((ks * 4 + qd) ^ (ar & 7)) * 8];
      }
#pragma unroll
      for (int nt = 0; nt < 4; nt++) {
        const short8 b = *(const short8*)&W1f[(size_t)(wn * 64 + nt * 16 + ln) * 1024 +
                                              kt + ks * 32 + qd * 8];
#pragma unroll
        for (int i = 0; i < 2; i++)
          acc[i][nt] = __builtin_amdgcn_mfma_f32_16x16x32_bf16(a[i], b, acc[i][nt], 0, 0, 0);
      }
    }
  }
#pragma unroll
  for (int i = 0; i < 2; i++)
#pragma unroll
    for (int nt = 0; nt < 4; nt++)
#pragma unroll
      for (int r = 0; r < 4; r++)
        G[(size_t)(m0 + wm * 32 + i * 16 + qd * 4 + r) * 128 + wn * 64 + nt * 16 + ln] =
            acc[i][nt][r];
}

// ---------------- fused scan step -------------------------------------------
// 1024 threads (16 waves), 64 rows/block, grid 256.
// flags: 1 = write q to Qout (last step), 2 = compute Gdst (all but last).
// P1: z2^T via swapped MFMA operands: acc[i][nt] holds
// z2[row=i*16+ln][col=wv*64+nt*16+qd*4+r]; wave owns a distinct 64-col W2t
// slice. G' (flags&2): G'[r][j] = (S[r] @ W21t[j] + c1[j]) * inv_r — K=128
// GEMM vs 32KB W21t, standard MFMA orientation, 2 col-tiles/wave.
// S LDS: 64 x 128 bf16, 8-col-unit XOR swizzle phys=(u&8)|((u^row)&7).
__global__ __launch_bounds__(1024, 4) void scan_fused(
    const float* __restrict__ Gsrc, float* __restrict__ Gdst,
    const u16* __restrict__ W21t, const u16* __restrict__ W2t,
    const float* __restrict__ b1, const float* __restrict__ b2,
    const float* __restrict__ fid, const float* __restrict__ c1,
    u16* __restrict__ Qout, int n, int flags) {
  __shared__ u16 S[64 * 128];  // 16KB
  __shared__ unsigned rmax[64];
  const int tid = threadIdx.x, lane = tid & 63, wv = tid >> 6;
  const int ln = lane & 15, qd = lane >> 4;
  const int r0 = blockIdx.x * 64;
  if (tid < 64) rmax[tid] = 0u;
  // ---- P0: f = G1[gr-n]|fid + G2[gr] + b1 ; sincos -> S (swizzled)
  {
    const int r = tid >> 4, js = (tid & 15) << 2;
    const int gr = r0 + r, tl = gr & (T_DIM - 1);
    const float* g1p = (tl >= n) ? &Gsrc[(size_t)(gr - n) * 128 + js] : &fid[js];
    const float4 g1 = *(const float4*)g1p;
    const float4 g2 = *(const float4*)&Gsrc[(size_t)gr * 128 + 64 + js];
    const float4 bb = *(const float4*)&b1[js];
    float f[4] = {g1.x + g2.x + bb.x, g1.y + g2.y + bb.y,
                  g1.z + g2.z + bb.z, g1.w + g2.w + bb.w};
    alignas(8) u16 sn[4], cs[4];
#pragma unroll
    for (int c = 0; c < 4; c++) {
      float sv, cv;
      __sincosf(f[c], &sv, &cv);
      sn[c] = f2bf(sv);
      cs[c] = f2bf(cv);
    }
    const int u = js >> 3, half = (js >> 2) & 1, rx = r & 7;
    const int ps = (u ^ rx) & 7;            // sin unit in [0,8)
    const int pc = 8 | ps;                  // cos unit in [8,16)
    *(uint2*)&S[r * 128 + ps * 8 + half * 4] = *(const uint2*)sn;
    *(uint2*)&S[r * 128 + pc * 8 + half * 4] = *(const uint2*)cs;
  }
  __syncthreads();
  // ---- P1: z2^T tiles via swapped MFMA operands. Wave owns 64 cols.
  const u16* w2b = W2t + (size_t)wv * 64 * 128;
  f32x4 acc[4][4] = {};
#pragma unroll
  for (int ks = 0; ks < 4; ks++) {
    short8 af[4];
#pragma unroll
    for (int i = 0; i < 4; i++) {
      const int ar = i * 16 + ln;
      const int u = ks * 4 + qd;
      af[i] = *(const short8*)&S[ar * 128 + ((u & 8) | ((u ^ ar) & 7)) * 8];
    }
#pragma unroll
    for (int nt = 0; nt < 4; nt++) {
      const short8 b = *(const short8*)&w2b[(size_t)(nt * 16 + ln) * 128 + ks * 32 + qd * 8];
#pragma unroll
      for (int i = 0; i < 4; i++)
        acc[i][nt] = __builtin_amdgcn_mfma_f32_16x16x32_bf16(b, af[i], acc[i][nt], 0, 0, 0);
    }
  }
  // bias + per-row absmax (row = i*16+ln; qd groups hold disjoint col sets)
  float mx[4] = {0.f, 0.f, 0.f, 0.f};
#pragma unroll
  for (int nt = 0; nt < 4; nt++) {
    const float4 bb = *(const float4*)&b2[wv * 64 + nt * 16 + qd * 4];
    const float br4[4] = {bb.x, bb.y, bb.z, bb.w};
#pragma unroll
    for (int i = 0; i < 4; i++)
#pragma unroll
      for (int r = 0; r < 4; r++) {
        const float v = acc[i][nt][r] + br4[r];
        acc[i][nt][r] = v;
        mx[i] = fmaxf(mx[i], fabsf(v));
      }
  }
#pragma unroll
  for (int i = 0; i < 4; i++) {
    float v = mx[i];
    v = fmaxf(v, __shfl_xor(v, 16, 64));
    v = fmaxf(v, __shfl_xor(v, 32, 64));
    if (lane < 16) atomicMax(&rmax[i * 16 + lane], __float_as_uint(v));
  }
  __syncthreads();  // rmax complete; S stays intact (no reuse)
  if (flags & 1) {  // last step: q = z2*inv straight from registers
    float inv[4];
#pragma unroll
    for (int i = 0; i < 4; i++)
      inv[i] = 1.0f / (__uint_as_float(rmax[i * 16 + ln]) + 1e-6f);
#pragma unroll
    for (int i = 0; i < 4; i++) {
      const int row = i * 16 + ln;
#pragma unroll
      for (int nt = 0; nt < 4; nt++) {
        const int col = wv * 64 + nt * 16 + qd * 4;
        uint2 pv;
        pv.x = (unsigned)f2bf(acc[i][nt][0] * inv[i]) |
               ((unsigned)f2bf(acc[i][nt][1] * inv[i]) << 16);
        pv.y = (unsigned)f2bf(acc[i][nt][2] * inv[i]) |
               ((unsigned)f2bf(acc[i][nt][3] * inv[i]) << 16);
        *(uint2*)&Qout[(size_t)(r0 + row) * 1024 + col] = pv;
      }
    }
  }
  if (flags & 2) {  // G' = (S @ W21t^T + c1) * inv : 64x128 out, K=128
    const int wm3 = wv & 3, wn3 = wv >> 2;  // 4 row-tiles x 4 col-pairs
    f32x4 g[2] = {};
#pragma unroll
    for (int ks = 0; ks < 4; ks++) {
      const int ar = wm3 * 16 + ln;
      const int u = ks * 4 + qd;
      const short8 a = *(const short8*)&S[ar * 128 + ((u & 8) | ((u ^ ar) & 7)) * 8];
#pragma unroll
      for (int c = 0; c < 2; c++) {
        const short8 b = *(const short8*)&W21t[(size_t)(wn3 * 32 + c * 16 + ln) * 128 +
                                               ks * 32 + qd * 8];
        g[c] = __builtin_amdgcn_mfma_f32_16x16x32_bf16(a, b, g[c], 0, 0, 0);
      }
    }
#pragma unroll
    for (int c = 0; c < 2; c++) {
      const int col = wn3 * 32 + c * 16 + ln;
      const float cb = c1[col];
#pragma unroll
      for (int r = 0; r < 4; r++) {
        const int row = wm3 * 16 + qd * 4 + r;
        const float invr = 1.0f / (__uint_as_float(rmax[row]) + 1e-6f);
        Gdst[(size_t)(r0 + row) * 128 + col] = (g[c][r] + cb) * invr;
      }
    }
  }
}

// ---------------- launch ----------------------------------------------------
extern "C" void kernel_launch(void* const* d_in, const int* in_sizes, int n_in,
                              void* d_out, int out_size, void* d_ws, size_t ws_size,
                              hipStream_t stream) {
  const float* x      = (const float*)d_in[0];
  const float* attn_W = (const float*)d_in[1];
  const float* attn_b = (const float*)d_in[2];
  const float* freq_W = (const float*)d_in[3];
  const float* freq_b = (const float*)d_in[4];
  const float* out_W  = (const float*)d_in[5];
  const float* out_b  = (const float*)d_in[6];
  const float* proj_W = (const float*)d_in[7];
  const float* proj_b = (const float*)d_in[8];
  const float* ident  = (const float*)d_in[9];
  float* out = (float*)d_out;

  const size_t RC = (size_t)R_ROWS * C_DIM;
  u16* Xb  = (u16*)d_ws;                     // 32MB
  u16* Qb  = Xb + RC;                        // 32MB
  u16* Vb  = Qb + RC;                        // 32MB
  u16* aWt = Vb + RC;                        // 4MB
  u16* pWt = aWt + (size_t)2048 * 1024;      // 2MB
  u16* w2t = pWt + (size_t)1024 * 1024;      // 256KB
  u16* w1f = w2t + (size_t)1024 * 128;       // 256KB
  float* Ga  = (float*)(w1f + (size_t)128 * 1024);  // 8MB
  float* Gb  = Ga + (size_t)R_ROWS * 128;           // 8MB
  float* fid = Gb + (size_t)R_ROWS * 128;           // 256B
  float* c1  = fid + 64;                            // 512B
  u16* W21t  = (u16*)(c1 + 128);                    // 32KB

  // prep
  cvt_bf16<<<8192, 256, 0, stream>>>(x, Xb, (int)(RC / 8));
  cvt_T<<<dim3(32, 64), 256, 0, stream>>>(attn_W, aWt, 1024, 2048);
  cvt_T<<<dim3(32, 32), 256, 0, stream>>>(proj_W, pWt, 1024, 1024);
  cvt_T<<<dim3(4, 32), 256, 0, stream>>>(out_W, w2t, 128, 1024);
  cvt_w1f<<<dim3(64, 2), 256, 0, stream>>>(freq_W, w1f);
  fid_kernel<<<1, 256, 0, stream>>>(ident, freq_W, fid);
  w21_kernel<<<128, 256, 0, stream>>>(out_W, out_b, w1f, W21t, c1);

  // q0, v
  gemm_qv_mfma<<<dim3(16, 128), 256, 0, stream>>>(Xb, aWt, attn_b, Qb, Vb);
  // G0 = q0 @ W1full
  g0_kernel<<<256, 256, 0, stream>>>(Qb, w1f, Ga);

  // 11 fused steps over G; last writes q into Qb (dead after g0)
  float* gs = Ga;
  float* gd = Gb;
  for (int n = 1; n < T_DIM; n <<= 1) {
    const int last = (n == 1024);
    scan_fused<<<256, 1024, 0, stream>>>(gs, gd, W21t, w2t, freq_b, out_b, fid,
                                         c1, Qb, n, last ? 1 : 2);
    float* t = gs; gs = gd; gd = t;
  }

  // Y = q*v ; out = Y @ proj_W + proj_b
  prod_bf16<<<8192, 256, 0, stream>>>(Qb, Vb, Xb, (int)(RC / 8));
  gemm_proj_mfma<<<dim3(8, 128), 256, 0, stream>>>(Xb, pWt, proj_b, out);
}